// Round 9
// baseline (289.808 us; speedup 1.0000x reference)
//
#include <hip/hip_runtime.h>
#include <math.h>

#define B_   32
#define N_   128
#define H_   100
#define ROWS (B_ * N_)    // 4096
#define RH   (ROWS * H_)  // 409600

// ---------------------------------------------------------------------------
// K1: hv = nodes@Wv, hw = nodes@Ww. 2 rows per 256-thread block; lane j = h.
__global__ __launch_bounds__(256, 6) void k_proj0(const float* __restrict__ nodes,
                                                  const float* __restrict__ Wv,
                                                  const float* __restrict__ Ww,
                                                  float* __restrict__ hv,
                                                  float* __restrict__ hw) {
    __shared__ float nod_s[2][H_];
    const int row0 = blockIdx.x * 2;
    const int t = threadIdx.x, r = t >> 7, j = t & 127;
    {
        const float4* ng = (const float4*)(nodes + (size_t)row0 * H_);
        if (t < 50) ((float4*)nod_s)[t] = ng[t];
    }
    __syncthreads();
    if (j >= H_) return;
    const float4* h4p = (const float4*)nod_s[r];
    float va = 0.f, wa = 0.f;
#pragma unroll 5
    for (int k4 = 0; k4 < 25; ++k4) {
        const float4 h4 = h4p[k4];
        const int k = k4 * 4;
        va = fmaf(h4.x, Wv[(k + 0) * H_ + j], va);
        wa = fmaf(h4.x, Ww[(k + 0) * H_ + j], wa);
        va = fmaf(h4.y, Wv[(k + 1) * H_ + j], va);
        wa = fmaf(h4.y, Ww[(k + 1) * H_ + j], wa);
        va = fmaf(h4.z, Wv[(k + 2) * H_ + j], va);
        wa = fmaf(h4.z, Ww[(k + 2) * H_ + j], wa);
        va = fmaf(h4.w, Wv[(k + 3) * H_ + j], va);
        wa = fmaf(h4.w, Ww[(k + 3) * H_ + j], wa);
    }
    hv[(size_t)(row0 + r) * H_ + j] = va;
    hw[(size_t)(row0 + r) * H_ + j] = wa;
}

// ---------------------------------------------------------------------------
// K2: one fused message pass. 128-thread blocks, ONE WAVE PER ROW (wv=t>>6),
// lane l handles h0=l and h1=l+64 (h1 masked for l>=36). e_s b128 broadcast
// is paid once per (row,w); edge mask + node mask computed in VALU.
// mode 1 -> tanh update + next-pass hv/hw projections;
// mode 2 -> tanh update + fused readout (atomics).
__global__ __launch_bounds__(128, 8) void k_pass(const float* __restrict__ edges,
                                                 const float* __restrict__ We,
                                                 const float* __restrict__ Wu,
                                                 const float* __restrict__ Wv,
                                                 const float* __restrict__ Ww,
                                                 const float* __restrict__ Wr,
                                                 const float* __restrict__ nodes,
                                                 float* __restrict__ hv_io,
                                                 const float* __restrict__ hw_in,
                                                 float* __restrict__ hw_out,
                                                 const float* __restrict__ hid_in,
                                                 float* __restrict__ hidden,
                                                 float* __restrict__ out,
                                                 int mode) {
    __shared__ float4 e_s[2][N_];      // 4 KB
    __shared__ float  hid_s[2][H_];    // 800 B
    __shared__ float  msg_s[2][H_];    // 800 B
    __shared__ float  hn_s[2][H_];     // 800 B
    __shared__ float  nod_s[2][H_];    // 800 B (mode 2)

    const int row0 = blockIdx.x * 2;
    const int b = row0 >> 7;
    const int t = threadIdx.x, wv = t >> 6, l = t & 63;
    const int row = row0 + wv;

    {   // stage both rows' edges (256 float4, 2 per thread) + hidden (+nodes)
        const float4* eg = (const float4*)(edges + (size_t)row0 * N_ * 4);
        ((float4*)e_s)[t]       = eg[t];
        ((float4*)e_s)[t + 128] = eg[t + 128];
        const float4* hg = (const float4*)(hid_in + (size_t)row0 * H_);
        if (t < 50) ((float4*)hid_s)[t] = hg[t];
        if (mode == 2 && t < 50)
            ((float4*)nod_s)[t] = ((const float4*)(nodes + (size_t)row0 * H_))[t];
    }
    __syncthreads();

    const int h0 = l;
    const bool a1 = (l < H_ - 64);            // l < 36
    const int h1 = a1 ? (l + 64) : (H_ - 1);  // clamped: loads stay valid

    const float hv0 = hv_io[(size_t)row * H_ + h0];
    const float hv1 = hv_io[(size_t)row * H_ + h1];
    const float we00 = We[0 * H_ + h0], we01 = We[1 * H_ + h0];
    const float we02 = We[2 * H_ + h0], we03 = We[3 * H_ + h0];
    const float we10 = We[0 * H_ + h1], we11 = We[1 * H_ + h1];
    const float we12 = We[2 * H_ + h1], we13 = We[3 * H_ + h1];

    float acc0 = 0.f, acc1 = 0.f, asum = 0.f;
    {
        const float* hp = hw_in + (size_t)b * N_ * H_;
#pragma unroll 4
        for (int w = 0; w < N_; ++w) {
            const float4 e = e_s[wv][w];          // LDS b128 broadcast (once/row)
            const float hw0 = hp[h0];             // coalesced 256B
            const float hw1 = hp[h1];             // coalesced 256B
            hp += H_;
            const float s = (e.x + e.y) + (e.z + e.w);
            asum += s;
            const float m = (s != 0.f) ? 1.f : 0.f;
            float p0 = hv0 + hw0, p1 = hv1 + hw1;
            p0 = fmaf(e.x, we00, p0); p1 = fmaf(e.x, we10, p1);
            p0 = fmaf(e.y, we01, p0); p1 = fmaf(e.y, we11, p1);
            p0 = fmaf(e.z, we02, p0); p1 = fmaf(e.z, we12, p1);
            p0 = fmaf(e.w, we03, p0); p1 = fmaf(e.w, we13, p1);
            acc0 = fmaf(m, fmaxf(p0, 0.f), acc0);
            acc1 = fmaf(m, fmaxf(p1, 0.f), acc1);
        }
    }
    msg_s[wv][h0] = acc0;
    if (a1) msg_s[wv][l + 64] = acc1;
    __syncthreads();

    // update: u = [hid, msg] @ Wu ; nh = nm ? tanh(u) : hid
    const float nm = (asum != 0.f) ? 1.f : 0.f;   // wave-uniform
    float u0 = 0.f, u1 = 0.f;
    {
        const float4* h4p = (const float4*)hid_s[wv];
        const float4* m4p = (const float4*)msg_s[wv];
#pragma unroll 5
        for (int k4 = 0; k4 < 25; ++k4) {
            const float4 h4 = h4p[k4];
            const int k = k4 * 4;
            u0 = fmaf(h4.x, Wu[(k + 0) * H_ + h0], u0);
            u1 = fmaf(h4.x, Wu[(k + 0) * H_ + h1], u1);
            u0 = fmaf(h4.y, Wu[(k + 1) * H_ + h0], u0);
            u1 = fmaf(h4.y, Wu[(k + 1) * H_ + h1], u1);
            u0 = fmaf(h4.z, Wu[(k + 2) * H_ + h0], u0);
            u1 = fmaf(h4.z, Wu[(k + 2) * H_ + h1], u1);
            u0 = fmaf(h4.w, Wu[(k + 3) * H_ + h0], u0);
            u1 = fmaf(h4.w, Wu[(k + 3) * H_ + h1], u1);
        }
#pragma unroll 5
        for (int k4 = 0; k4 < 25; ++k4) {
            const float4 m4 = m4p[k4];
            const int k = H_ + k4 * 4;
            u0 = fmaf(m4.x, Wu[(k + 0) * H_ + h0], u0);
            u1 = fmaf(m4.x, Wu[(k + 0) * H_ + h1], u1);
            u0 = fmaf(m4.y, Wu[(k + 1) * H_ + h0], u0);
            u1 = fmaf(m4.y, Wu[(k + 1) * H_ + h1], u1);
            u0 = fmaf(m4.z, Wu[(k + 2) * H_ + h0], u0);
            u1 = fmaf(m4.z, Wu[(k + 2) * H_ + h1], u1);
            u0 = fmaf(m4.w, Wu[(k + 3) * H_ + h0], u0);
            u1 = fmaf(m4.w, Wu[(k + 3) * H_ + h1], u1);
        }
    }
    const float nh0 = (nm != 0.f) ? tanhf(u0) : hid_s[wv][h0];
    const float nh1 = (nm != 0.f) ? tanhf(u1) : hid_s[wv][h1];
    hn_s[wv][h0] = nh0;
    if (a1) hn_s[wv][l + 64] = nh1;
    if (mode == 1) {
        hidden[(size_t)row * H_ + h0] = nh0;
        if (a1) hidden[(size_t)row * H_ + l + 64] = nh1;
    }
    __syncthreads();

    if (mode == 1) {        // next pass's hv/hw from fresh hidden (own row)
        const float4* h4p = (const float4*)hn_s[wv];
        float va0 = 0, va1 = 0, wa0 = 0, wa1 = 0;
#pragma unroll 5
        for (int k4 = 0; k4 < 25; ++k4) {
            const float4 h4 = h4p[k4];
            const int k = k4 * 4;
            va0 = fmaf(h4.x, Wv[(k + 0) * H_ + h0], va0);
            va1 = fmaf(h4.x, Wv[(k + 0) * H_ + h1], va1);
            wa0 = fmaf(h4.x, Ww[(k + 0) * H_ + h0], wa0);
            wa1 = fmaf(h4.x, Ww[(k + 0) * H_ + h1], wa1);
            va0 = fmaf(h4.y, Wv[(k + 1) * H_ + h0], va0);
            va1 = fmaf(h4.y, Wv[(k + 1) * H_ + h1], va1);
            wa0 = fmaf(h4.y, Ww[(k + 1) * H_ + h0], wa0);
            wa1 = fmaf(h4.y, Ww[(k + 1) * H_ + h1], wa1);
            va0 = fmaf(h4.z, Wv[(k + 2) * H_ + h0], va0);
            va1 = fmaf(h4.z, Wv[(k + 2) * H_ + h1], va1);
            wa0 = fmaf(h4.z, Ww[(k + 2) * H_ + h0], wa0);
            wa1 = fmaf(h4.z, Ww[(k + 2) * H_ + h1], wa1);
            va0 = fmaf(h4.w, Wv[(k + 3) * H_ + h0], va0);
            va1 = fmaf(h4.w, Wv[(k + 3) * H_ + h1], va1);
            wa0 = fmaf(h4.w, Ww[(k + 3) * H_ + h0], wa0);
            wa1 = fmaf(h4.w, Ww[(k + 3) * H_ + h1], wa1);
        }
        hv_io[(size_t)row * H_ + h0] = va0;       // row-local: safe in-place
        hw_out[(size_t)row * H_ + h0] = wa0;      // double-buffered
        if (a1) {
            hv_io[(size_t)row * H_ + l + 64] = va1;
            hw_out[(size_t)row * H_ + l + 64] = wa1;
        }
    } else {                // mode 2: fused readout, per-wave atomics
        const float4* h4p = (const float4*)hn_s[wv];
        const float4* n4p = (const float4*)nod_s[wv];
        float r0 = 0.f, r1 = 0.f;
#pragma unroll 5
        for (int k4 = 0; k4 < 25; ++k4) {
            const float4 h4 = h4p[k4];
            const int k = k4 * 4;
            r0 = fmaf(h4.x, Wr[(k + 0) * H_ + h0], r0);
            r1 = fmaf(h4.x, Wr[(k + 0) * H_ + h1], r1);
            r0 = fmaf(h4.y, Wr[(k + 1) * H_ + h0], r0);
            r1 = fmaf(h4.y, Wr[(k + 1) * H_ + h1], r1);
            r0 = fmaf(h4.z, Wr[(k + 2) * H_ + h0], r0);
            r1 = fmaf(h4.z, Wr[(k + 2) * H_ + h1], r1);
            r0 = fmaf(h4.w, Wr[(k + 3) * H_ + h0], r0);
            r1 = fmaf(h4.w, Wr[(k + 3) * H_ + h1], r1);
        }
#pragma unroll 5
        for (int k4 = 0; k4 < 25; ++k4) {
            const float4 n4 = n4p[k4];
            const int k = H_ + k4 * 4;
            r0 = fmaf(n4.x, Wr[(k + 0) * H_ + h0], r0);
            r1 = fmaf(n4.x, Wr[(k + 0) * H_ + h1], r1);
            r0 = fmaf(n4.y, Wr[(k + 1) * H_ + h0], r0);
            r1 = fmaf(n4.y, Wr[(k + 1) * H_ + h1], r1);
            r0 = fmaf(n4.z, Wr[(k + 2) * H_ + h0], r0);
            r1 = fmaf(n4.z, Wr[(k + 2) * H_ + h1], r1);
            r0 = fmaf(n4.w, Wr[(k + 3) * H_ + h0], r0);
            r1 = fmaf(n4.w, Wr[(k + 3) * H_ + h1], r1);
        }
        atomicAdd(out + b * H_ + h0, nm * fmaxf(r0, 0.f));
        if (a1) atomicAdd(out + b * H_ + l + 64, nm * fmaxf(r1, 0.f));
    }
}

// ---------------------------------------------------------------------------
extern "C" void kernel_launch(void* const* d_in, const int* in_sizes, int n_in,
                              void* d_out, int out_size, void* d_ws, size_t ws_size,
                              hipStream_t stream) {
    const float* nodes = (const float*)d_in[0];
    const float* edges = (const float*)d_in[1];
    const float* Wv    = (const float*)d_in[2];
    const float* Ww    = (const float*)d_in[3];
    const float* We    = (const float*)d_in[4];
    const float* Wu    = (const float*)d_in[5];
    const float* Wr    = (const float*)d_in[6];
    float* out = (float*)d_out;

    float* hidden = (float*)d_ws;     // RH
    float* hv     = hidden + RH;      // RH
    float* hwA    = hv + RH;          // RH
    float* hwB    = hwA + RH;         // RH

    hipMemsetAsync(d_out, 0, (size_t)out_size * sizeof(float), stream);

    k_proj0<<<ROWS / 2, 256, 0, stream>>>(nodes, Wv, Ww, hv, hwA);

    k_pass<<<ROWS / 2, 128, 0, stream>>>(edges, We, Wu, Wv, Ww, Wr, nodes,
                                         hv, hwA, hwB, nodes, hidden, out, 1);
    k_pass<<<ROWS / 2, 128, 0, stream>>>(edges, We, Wu, Wv, Ww, Wr, nodes,
                                         hv, hwB, hwA, hidden, hidden, out, 1);
    k_pass<<<ROWS / 2, 128, 0, stream>>>(edges, We, Wu, Wv, Ww, Wr, nodes,
                                         hv, hwA, hwB, hidden, hidden, out, 2);
}

// Round 10
// 214.497 us; speedup vs baseline: 1.3511x; 1.3511x over previous
//
#include <hip/hip_runtime.h>
#include <math.h>

#define B_   32
#define N_   128
#define H_   100
#define ROWS (B_ * N_)    // 4096
#define RH   (ROWS * H_)  // 409600

// ---------------------------------------------------------------------------
// K1: hv = nodes@Wv, hw = nodes@Ww. 2 rows per 256-thread block; lane j = h.
__global__ __launch_bounds__(256, 6) void k_proj0(const float* __restrict__ nodes,
                                                  const float* __restrict__ Wv,
                                                  const float* __restrict__ Ww,
                                                  float* __restrict__ hv,
                                                  float* __restrict__ hw) {
    __shared__ float nod_s[2][H_];
    const int row0 = blockIdx.x * 2;
    const int t = threadIdx.x, r = t >> 7, j = t & 127;
    {
        const float4* ng = (const float4*)(nodes + (size_t)row0 * H_);
        if (t < 50) ((float4*)nod_s)[t] = ng[t];
    }
    __syncthreads();
    if (j >= H_) return;
    const float4* h4p = (const float4*)nod_s[r];
    float va = 0.f, wa = 0.f;
#pragma unroll 5
    for (int k4 = 0; k4 < 25; ++k4) {
        const float4 h4 = h4p[k4];
        const int k = k4 * 4;
        va = fmaf(h4.x, Wv[(k + 0) * H_ + j], va);
        wa = fmaf(h4.x, Ww[(k + 0) * H_ + j], wa);
        va = fmaf(h4.y, Wv[(k + 1) * H_ + j], va);
        wa = fmaf(h4.y, Ww[(k + 1) * H_ + j], wa);
        va = fmaf(h4.z, Wv[(k + 2) * H_ + j], va);
        wa = fmaf(h4.z, Ww[(k + 2) * H_ + j], wa);
        va = fmaf(h4.w, Wv[(k + 3) * H_ + j], va);
        wa = fmaf(h4.w, Ww[(k + 3) * H_ + j], wa);
    }
    hv[(size_t)(row0 + r) * H_ + j] = va;
    hw[(size_t)(row0 + r) * H_ + j] = wa;
}

// ---------------------------------------------------------------------------
// K2: one fused message pass (r8 skeleton, w-split message phase).
// 256-thread blocks, 2 rows. MESSAGE phase: wave wv serves row wv>>1 and
// w-half wv&1; lane l -> h-pair (2l, 2l+1); e_s b128 broadcast read ONCE per
// (row, w); mask + adjacency row-sum in VALU; partials combined via LDS.
// UPDATE/PROJ/READOUT phases: r8-verbatim (r = t>>7, j = t&127).
__global__ __launch_bounds__(256, 6) void k_pass(const float* __restrict__ edges,
                                                 const float* __restrict__ We,
                                                 const float* __restrict__ Wu,
                                                 const float* __restrict__ Wv,
                                                 const float* __restrict__ Ww,
                                                 const float* __restrict__ Wr,
                                                 const float* __restrict__ nodes,
                                                 float* __restrict__ hv_io,
                                                 const float* __restrict__ hw_in,
                                                 float* __restrict__ hw_out,
                                                 const float* __restrict__ hid_in,
                                                 float* __restrict__ hidden,
                                                 float* __restrict__ out,
                                                 int mode) {
    __shared__ float4 e_s[2][N_];      // 4 KB
    __shared__ float  hid_s[2][H_];    // 800 B
    __shared__ float  msgp_s[4][H_];   // 1.6 KB per-wave partial messages
    __shared__ float  msg_s[2][H_];    // 800 B
    __shared__ float  hn_s[2][H_];     // 800 B
    __shared__ float  nod_s[2][H_];    // 800 B (mode 2)
    __shared__ float  red_s[2][H_];    // 800 B (mode 2)
    __shared__ float  asum_s[4];

    const int row0 = blockIdx.x * 2;
    const int b = row0 >> 7;
    const int t = threadIdx.x, r = t >> 7, j = t & 127;
    const int wv = t >> 6, l = t & 63;
    const int rw = wv >> 1;            // message-phase row (0/1)
    const int half = wv & 1;           // message-phase w-half
    const int roww = row0 + rw;
    const int row = row0 + r;
    const bool act = (j < H_);
    const bool mact = (l < 50);
    const int ll = mact ? l : 49;      // clamped: keeps loads in-bounds

    {   // stage both rows' edges (256 coalesced float4) + hidden (+nodes)
        const float4* eg = (const float4*)(edges + (size_t)row0 * N_ * 4);
        ((float4*)e_s)[t] = eg[t];
        const float4* hg = (const float4*)(hid_in + (size_t)row0 * H_);
        if (t < 50) ((float4*)hid_s)[t] = hg[t];
        if (mode == 2 && t < 50)
            ((float4*)nod_s)[t] = ((const float4*)(nodes + (size_t)row0 * H_))[t];
    }
    __syncthreads();

    // ---- message phase (w-split) ----
    {
        const float2 hv2 = *(const float2*)(hv_io + (size_t)roww * H_ + 2 * ll);
        const float2 we0 = *(const float2*)(We + 0 * H_ + 2 * ll);
        const float2 we1 = *(const float2*)(We + 1 * H_ + 2 * ll);
        const float2 we2 = *(const float2*)(We + 2 * H_ + 2 * ll);
        const float2 we3 = *(const float2*)(We + 3 * H_ + 2 * ll);
        const int w0 = half * 64;
        const float* hwbase = hw_in + ((size_t)b * N_ + w0) * H_ + 2 * ll;
        float acc0 = 0.f, acc1 = 0.f, asum = 0.f;
#pragma unroll 8
        for (int w = 0; w < 64; ++w) {
            const float4 e = e_s[rw][w0 + w];               // b128 broadcast
            const float2 hw2 = *(const float2*)(hwbase + w * H_);  // coalesced
            const float s = (e.x + e.y) + (e.z + e.w);
            asum += s;
            const float m = (s != 0.f) ? 1.f : 0.f;
            float p0 = hv2.x + hw2.x, p1 = hv2.y + hw2.y;
            p0 = fmaf(e.x, we0.x, p0); p1 = fmaf(e.x, we0.y, p1);
            p0 = fmaf(e.y, we1.x, p0); p1 = fmaf(e.y, we1.y, p1);
            p0 = fmaf(e.z, we2.x, p0); p1 = fmaf(e.z, we2.y, p1);
            p0 = fmaf(e.w, we3.x, p0); p1 = fmaf(e.w, we3.y, p1);
            acc0 = fmaf(m, fmaxf(p0, 0.f), acc0);
            acc1 = fmaf(m, fmaxf(p1, 0.f), acc1);
        }
        if (mact) *(float2*)(&msgp_s[wv][2 * l]) = make_float2(acc0, acc1);
        if (l == 0) asum_s[wv] = asum;   // wave-uniform (e broadcast)
    }
    __syncthreads();

    // combine partial messages (r8 j-mapping)
    if (act) msg_s[r][j] = msgp_s[2 * r][j] + msgp_s[2 * r + 1][j];
    __syncthreads();

    const float nm = ((asum_s[2 * r] + asum_s[2 * r + 1]) != 0.f) ? 1.f : 0.f;

    // ---- update: u = [hid, msg] @ Wu ; nh = nm ? tanh(u) : hid ----
    if (act) {
        const float4* h4p = (const float4*)hid_s[r];
        const float4* m4p = (const float4*)msg_s[r];
        float u = 0.f;
#pragma unroll 5
        for (int k4 = 0; k4 < 25; ++k4) {
            const float4 h4 = h4p[k4];
            const int k = k4 * 4;
            u = fmaf(h4.x, Wu[(k + 0) * H_ + j], u);
            u = fmaf(h4.y, Wu[(k + 1) * H_ + j], u);
            u = fmaf(h4.z, Wu[(k + 2) * H_ + j], u);
            u = fmaf(h4.w, Wu[(k + 3) * H_ + j], u);
        }
#pragma unroll 5
        for (int k4 = 0; k4 < 25; ++k4) {
            const float4 m4 = m4p[k4];
            const int k = H_ + k4 * 4;
            u = fmaf(m4.x, Wu[(k + 0) * H_ + j], u);
            u = fmaf(m4.y, Wu[(k + 1) * H_ + j], u);
            u = fmaf(m4.z, Wu[(k + 2) * H_ + j], u);
            u = fmaf(m4.w, Wu[(k + 3) * H_ + j], u);
        }
        const float nh = (nm != 0.f) ? tanhf(u) : hid_s[r][j];
        hn_s[r][j] = nh;
        if (mode == 1) hidden[(size_t)row * H_ + j] = nh;
    }
    __syncthreads();

    if (mode == 1) {        // next pass's hv/hw from fresh hidden (own rows)
        if (act) {
            const float4* h4p = (const float4*)hn_s[r];
            float va = 0.f, wa = 0.f;
#pragma unroll 5
            for (int k4 = 0; k4 < 25; ++k4) {
                const float4 h4 = h4p[k4];
                const int k = k4 * 4;
                va = fmaf(h4.x, Wv[(k + 0) * H_ + j], va);
                wa = fmaf(h4.x, Ww[(k + 0) * H_ + j], wa);
                va = fmaf(h4.y, Wv[(k + 1) * H_ + j], va);
                wa = fmaf(h4.y, Ww[(k + 1) * H_ + j], wa);
                va = fmaf(h4.z, Wv[(k + 2) * H_ + j], va);
                wa = fmaf(h4.z, Ww[(k + 2) * H_ + j], wa);
                va = fmaf(h4.w, Wv[(k + 3) * H_ + j], va);
                wa = fmaf(h4.w, Ww[(k + 3) * H_ + j], wa);
            }
            hv_io[(size_t)row * H_ + j] = va;     // row-local: safe in-place
            hw_out[(size_t)row * H_ + j] = wa;    // double-buffered
        }
    } else {                // mode 2: fused readout
        if (act) {
            const float4* h4p = (const float4*)hn_s[r];
            const float4* n4p = (const float4*)nod_s[r];
            float u = 0.f;
#pragma unroll 5
            for (int k4 = 0; k4 < 25; ++k4) {
                const float4 h4 = h4p[k4];
                const int k = k4 * 4;
                u = fmaf(h4.x, Wr[(k + 0) * H_ + j], u);
                u = fmaf(h4.y, Wr[(k + 1) * H_ + j], u);
                u = fmaf(h4.z, Wr[(k + 2) * H_ + j], u);
                u = fmaf(h4.w, Wr[(k + 3) * H_ + j], u);
            }
#pragma unroll 5
            for (int k4 = 0; k4 < 25; ++k4) {
                const float4 n4 = n4p[k4];
                const int k = H_ + k4 * 4;
                u = fmaf(n4.x, Wr[(k + 0) * H_ + j], u);
                u = fmaf(n4.y, Wr[(k + 1) * H_ + j], u);
                u = fmaf(n4.z, Wr[(k + 2) * H_ + j], u);
                u = fmaf(n4.w, Wr[(k + 3) * H_ + j], u);
            }
            red_s[r][j] = nm * fmaxf(u, 0.f);
        }
        __syncthreads();
        if (t < H_) atomicAdd(out + b * H_ + t, red_s[0][t] + red_s[1][t]);
    }
}

// ---------------------------------------------------------------------------
extern "C" void kernel_launch(void* const* d_in, const int* in_sizes, int n_in,
                              void* d_out, int out_size, void* d_ws, size_t ws_size,
                              hipStream_t stream) {
    const float* nodes = (const float*)d_in[0];
    const float* edges = (const float*)d_in[1];
    const float* Wv    = (const float*)d_in[2];
    const float* Ww    = (const float*)d_in[3];
    const float* We    = (const float*)d_in[4];
    const float* Wu    = (const float*)d_in[5];
    const float* Wr    = (const float*)d_in[6];
    float* out = (float*)d_out;

    float* hidden = (float*)d_ws;     // RH
    float* hv     = hidden + RH;      // RH
    float* hwA    = hv + RH;          // RH
    float* hwB    = hwA + RH;         // RH

    hipMemsetAsync(d_out, 0, (size_t)out_size * sizeof(float), stream);

    k_proj0<<<ROWS / 2, 256, 0, stream>>>(nodes, Wv, Ww, hv, hwA);

    k_pass<<<ROWS / 2, 256, 0, stream>>>(edges, We, Wu, Wv, Ww, Wr, nodes,
                                         hv, hwA, hwB, nodes, hidden, out, 1);
    k_pass<<<ROWS / 2, 256, 0, stream>>>(edges, We, Wu, Wv, Ww, Wr, nodes,
                                         hv, hwB, hwA, hidden, hidden, out, 1);
    k_pass<<<ROWS / 2, 256, 0, stream>>>(edges, We, Wu, Wv, Ww, Wr, nodes,
                                         hv, hwA, hwB, hidden, hidden, out, 2);
}

// Round 12
// 207.851 us; speedup vs baseline: 1.3943x; 1.0320x over previous
//
#include <hip/hip_runtime.h>
#include <math.h>

#define B_   32
#define N_   128
#define H_   100
#define ROWS (B_ * N_)    // 4096
#define RH   (ROWS * H_)  // 409600
#define OUTSZ (B_ * H_)   // 3200

// ---------------------------------------------------------------------------
// K1: hv = nodes@Wv, hw = nodes@Ww. 2 rows per 256-thread block; lane j = h.
// Also zero-initializes out (poisoned 0xAA before every timed call).
__global__ __launch_bounds__(256, 6) void k_proj0(const float* __restrict__ nodes,
                                                  const float* __restrict__ Wv,
                                                  const float* __restrict__ Ww,
                                                  float* __restrict__ hv,
                                                  float* __restrict__ hw,
                                                  float* __restrict__ out) {
    __shared__ float nod_s[2][H_];
    const int row0 = blockIdx.x * 2;
    const int t = threadIdx.x, r = t >> 7, j = t & 127;
    {   // zero out[] (runs 3 dispatches before any atomicAdd; stream-ordered)
        const int gid = blockIdx.x * 256 + t;
        if (gid < OUTSZ) out[gid] = 0.f;
    }
    {
        const float4* ng = (const float4*)(nodes + (size_t)row0 * H_);
        if (t < 50) ((float4*)nod_s)[t] = ng[t];
    }
    __syncthreads();
    if (j >= H_) return;
    const float4* h4p = (const float4*)nod_s[r];
    float va = 0.f, wa = 0.f;
#pragma unroll 5
    for (int k4 = 0; k4 < 25; ++k4) {
        const float4 h4 = h4p[k4];
        const int k = k4 * 4;
        va = fmaf(h4.x, Wv[(k + 0) * H_ + j], va);
        wa = fmaf(h4.x, Ww[(k + 0) * H_ + j], wa);
        va = fmaf(h4.y, Wv[(k + 1) * H_ + j], va);
        wa = fmaf(h4.y, Ww[(k + 1) * H_ + j], wa);
        va = fmaf(h4.z, Wv[(k + 2) * H_ + j], va);
        wa = fmaf(h4.z, Ww[(k + 2) * H_ + j], wa);
        va = fmaf(h4.w, Wv[(k + 3) * H_ + j], va);
        wa = fmaf(h4.w, Ww[(k + 3) * H_ + j], wa);
    }
    hv[(size_t)(row0 + r) * H_ + j] = va;
    hw[(size_t)(row0 + r) * H_ + j] = wa;
}

// ---------------------------------------------------------------------------
// K2: one fused message pass (r8 skeleton). 2 rows per 256-thread block
// (r = t>>7, j = t&127, lane j = h). Message loop: e_s b128 broadcast from
// LDS; EDGE MASK COMPUTED IN VALU (m_s LDS read eliminated — 23.8k CU-serial
// LDS cyc -> 8.2k parallel VALU cyc/SIMD); hw coalesced scalar from global.
// Node mask from stage-time shuffle-reduce. Then tanh update; mode 1 ->
// next-pass hv/hw projections; mode 2 -> fused readout.
__global__ __launch_bounds__(256, 6) void k_pass(const float* __restrict__ edges,
                                                 const float* __restrict__ We,
                                                 const float* __restrict__ Wu,
                                                 const float* __restrict__ Wv,
                                                 const float* __restrict__ Ww,
                                                 const float* __restrict__ Wr,
                                                 const float* __restrict__ nodes,
                                                 float* __restrict__ hv_io,
                                                 const float* __restrict__ hw_in,
                                                 float* __restrict__ hw_out,
                                                 const float* __restrict__ hid_in,
                                                 float* __restrict__ hidden,
                                                 float* __restrict__ out,
                                                 int mode) {
    __shared__ float4 e_s[2][N_];      // 4 KB
    __shared__ float  asum_part[4];    // per-wave partial row sums
    __shared__ float  hid_s[2][H_];
    __shared__ float  msg_s[2][H_];
    __shared__ float  hn_s[2][H_];
    __shared__ float  nod_s[2][H_];    // mode 2 only
    __shared__ float  red_s[2][H_];    // mode 2 only

    const int row0 = blockIdx.x * 2;
    const int b = row0 >> 7;
    const int t = threadIdx.x, r = t >> 7, j = t & 127;
    const int wv = t >> 6, lane = t & 63;
    const int row = row0 + r;
    const bool act = (j < H_);

    {   // stage both rows' edges; shuffle-reduce adjacency row sums
        const float4* eg = (const float4*)(edges + (size_t)row0 * N_ * 4);
        const float4 e = eg[t];                   // t == r*128 + j, coalesced
        e_s[r][j] = e;
        float s = (e.x + e.y) + (e.z + e.w);
#pragma unroll
        for (int off = 32; off > 0; off >>= 1) s += __shfl_down(s, off);
        if (lane == 0) asum_part[wv] = s;
    }
    {   // stage pre-update hidden rows (50 float4); nodes too if readout pass
        const float4* hg = (const float4*)(hid_in + (size_t)row0 * H_);
        if (t < 50) ((float4*)hid_s)[t] = hg[t];
        if (mode == 2) {
            const float4* ng = (const float4*)(nodes + (size_t)row0 * H_);
            if (t < 50) ((float4*)nod_s)[t] = ng[t];
        }
    }
    __syncthreads();

    const float nm = ((asum_part[2 * r] + asum_part[2 * r + 1]) != 0.f) ? 1.f : 0.f;

    if (act) {
        const float hvv = hv_io[(size_t)row * H_ + j];
        const float we0 = We[0 * H_ + j], we1 = We[1 * H_ + j];
        const float we2 = We[2 * H_ + j], we3 = We[3 * H_ + j];
        const float* hwp = hw_in + (size_t)b * N_ * H_ + j;
        float acc = 0.f;
#pragma unroll 8
        for (int w = 0; w < N_; ++w) {
            const float4 e = e_s[r][w];           // LDS b128 broadcast
            const float  hww = hwp[w * H_];       // coalesced 400B/wave-pair
            const float  s = (e.x + e.y) + (e.z + e.w);
            const float  m = (s != 0.f) ? 1.f : 0.f;   // VALU, not LDS
            float p = hvv + hww;
            p = fmaf(e.x, we0, p);
            p = fmaf(e.y, we1, p);
            p = fmaf(e.z, we2, p);
            p = fmaf(e.w, we3, p);
            acc = fmaf(m, fmaxf(p, 0.f), acc);
        }
        msg_s[r][j] = acc;
    }
    __syncthreads();

    if (act) {
        const float4* h4p = (const float4*)hid_s[r];
        const float4* m4p = (const float4*)msg_s[r];
        float u = 0.f;
#pragma unroll 5
        for (int k4 = 0; k4 < 25; ++k4) {
            const float4 h4 = h4p[k4];
            const int k = k4 * 4;
            u = fmaf(h4.x, Wu[(k + 0) * H_ + j], u);
            u = fmaf(h4.y, Wu[(k + 1) * H_ + j], u);
            u = fmaf(h4.z, Wu[(k + 2) * H_ + j], u);
            u = fmaf(h4.w, Wu[(k + 3) * H_ + j], u);
        }
#pragma unroll 5
        for (int k4 = 0; k4 < 25; ++k4) {
            const float4 m4 = m4p[k4];
            const int k = H_ + k4 * 4;
            u = fmaf(m4.x, Wu[(k + 0) * H_ + j], u);
            u = fmaf(m4.y, Wu[(k + 1) * H_ + j], u);
            u = fmaf(m4.z, Wu[(k + 2) * H_ + j], u);
            u = fmaf(m4.w, Wu[(k + 3) * H_ + j], u);
        }
        const float nh = (nm != 0.f) ? tanhf(u) : hid_s[r][j];
        hn_s[r][j] = nh;
        if (mode == 1) hidden[(size_t)row * H_ + j] = nh;
    }
    __syncthreads();

    if (mode == 1) {        // next pass's hv/hw from fresh hidden (own rows)
        if (act) {
            const float4* h4p = (const float4*)hn_s[r];
            float va = 0.f, wa = 0.f;
#pragma unroll 5
            for (int k4 = 0; k4 < 25; ++k4) {
                const float4 h4 = h4p[k4];
                const int k = k4 * 4;
                va = fmaf(h4.x, Wv[(k + 0) * H_ + j], va);
                wa = fmaf(h4.x, Ww[(k + 0) * H_ + j], wa);
                va = fmaf(h4.y, Wv[(k + 1) * H_ + j], va);
                wa = fmaf(h4.y, Ww[(k + 1) * H_ + j], wa);
                va = fmaf(h4.z, Wv[(k + 2) * H_ + j], va);
                wa = fmaf(h4.z, Ww[(k + 2) * H_ + j], wa);
                va = fmaf(h4.w, Wv[(k + 3) * H_ + j], va);
                wa = fmaf(h4.w, Ww[(k + 3) * H_ + j], wa);
            }
            hv_io[(size_t)row * H_ + j] = va;     // row-local: safe in-place
            hw_out[(size_t)row * H_ + j] = wa;    // double-buffered
        }
    } else {                // mode 2: fused readout
        if (act) {
            const float4* h4p = (const float4*)hn_s[r];
            const float4* n4p = (const float4*)nod_s[r];
            float u = 0.f;
#pragma unroll 5
            for (int k4 = 0; k4 < 25; ++k4) {
                const float4 h4 = h4p[k4];
                const int k = k4 * 4;
                u = fmaf(h4.x, Wr[(k + 0) * H_ + j], u);
                u = fmaf(h4.y, Wr[(k + 1) * H_ + j], u);
                u = fmaf(h4.z, Wr[(k + 2) * H_ + j], u);
                u = fmaf(h4.w, Wr[(k + 3) * H_ + j], u);
            }
#pragma unroll 5
            for (int k4 = 0; k4 < 25; ++k4) {
                const float4 n4 = n4p[k4];
                const int k = H_ + k4 * 4;
                u = fmaf(n4.x, Wr[(k + 0) * H_ + j], u);
                u = fmaf(n4.y, Wr[(k + 1) * H_ + j], u);
                u = fmaf(n4.z, Wr[(k + 2) * H_ + j], u);
                u = fmaf(n4.w, Wr[(k + 3) * H_ + j], u);
            }
            red_s[r][j] = nm * fmaxf(u, 0.f);
        }
        __syncthreads();
        if (t < H_) atomicAdd(out + b * H_ + t, red_s[0][t] + red_s[1][t]);
    }
}

// ---------------------------------------------------------------------------
extern "C" void kernel_launch(void* const* d_in, const int* in_sizes, int n_in,
                              void* d_out, int out_size, void* d_ws, size_t ws_size,
                              hipStream_t stream) {
    const float* nodes = (const float*)d_in[0];
    const float* edges = (const float*)d_in[1];
    const float* Wv    = (const float*)d_in[2];
    const float* Ww    = (const float*)d_in[3];
    const float* We    = (const float*)d_in[4];
    const float* Wu    = (const float*)d_in[5];
    const float* Wr    = (const float*)d_in[6];
    float* out = (float*)d_out;

    float* hidden = (float*)d_ws;     // RH
    float* hv     = hidden + RH;      // RH
    float* hwA    = hv + RH;          // RH
    float* hwB    = hwA + RH;         // RH

    k_proj0<<<ROWS / 2, 256, 0, stream>>>(nodes, Wv, Ww, hv, hwA, out);

    k_pass<<<ROWS / 2, 256, 0, stream>>>(edges, We, Wu, Wv, Ww, Wr, nodes,
                                         hv, hwA, hwB, nodes, hidden, out, 1);
    k_pass<<<ROWS / 2, 256, 0, stream>>>(edges, We, Wu, Wv, Ww, Wr, nodes,
                                         hv, hwB, hwA, hidden, hidden, out, 1);
    k_pass<<<ROWS / 2, 256, 0, stream>>>(edges, We, Wu, Wv, Ww, Wr, nodes,
                                         hv, hwA, hwB, hidden, hidden, out, 2);
}

// Round 13
// 196.043 us; speedup vs baseline: 1.4783x; 1.0602x over previous
//
#include <hip/hip_runtime.h>
#include <math.h>

#define B_   32
#define N_   128
#define H_   100
#define ROWS (B_ * N_)    // 4096
#define RH   (ROWS * H_)  // 409600
#define OUTSZ (B_ * H_)   // 3200

// ---------------------------------------------------------------------------
// K1: hv = nodes@Wv, hw = nodes@Ww. 2 rows per 256-thread block; lane j = h.
// Also zero-initializes out (poisoned 0xAA before every timed call).
__global__ __launch_bounds__(256, 6) void k_proj0(const float* __restrict__ nodes,
                                                  const float* __restrict__ Wv,
                                                  const float* __restrict__ Ww,
                                                  float* __restrict__ hv,
                                                  float* __restrict__ hw,
                                                  float* __restrict__ out) {
    __shared__ float nod_s[2][H_];
    const int row0 = blockIdx.x * 2;
    const int t = threadIdx.x, r = t >> 7, j = t & 127;
    {   // zero out[] (3 dispatches before any atomicAdd; stream-ordered)
        const int gid = blockIdx.x * 256 + t;
        if (gid < OUTSZ) out[gid] = 0.f;
    }
    {
        const float4* ng = (const float4*)(nodes + (size_t)row0 * H_);
        if (t < 50) ((float4*)nod_s)[t] = ng[t];
    }
    __syncthreads();
    if (j >= H_) return;
    const float4* h4p = (const float4*)nod_s[r];
    float va = 0.f, wa = 0.f;
#pragma unroll 5
    for (int k4 = 0; k4 < 25; ++k4) {
        const float4 h4 = h4p[k4];
        const int k = k4 * 4;
        va = fmaf(h4.x, Wv[(k + 0) * H_ + j], va);
        wa = fmaf(h4.x, Ww[(k + 0) * H_ + j], wa);
        va = fmaf(h4.y, Wv[(k + 1) * H_ + j], va);
        wa = fmaf(h4.y, Ww[(k + 1) * H_ + j], wa);
        va = fmaf(h4.z, Wv[(k + 2) * H_ + j], va);
        wa = fmaf(h4.z, Ww[(k + 2) * H_ + j], wa);
        va = fmaf(h4.w, Wv[(k + 3) * H_ + j], va);
        wa = fmaf(h4.w, Ww[(k + 3) * H_ + j], wa);
    }
    hv[(size_t)(row0 + r) * H_ + j] = va;
    hw[(size_t)(row0 + r) * H_ + j] = wa;
}

// ---------------------------------------------------------------------------
// K2: one fused message pass (r8 skeleton). 2 rows per 256-thread block
// (r = t>>7, j = t&127, lane j = h). Message loop: e_s b128 broadcast from
// LDS + hw coalesced scalar from global; edge mask as BALLOT BITS read from
// SGPR (scalar pipe) — no m_s LDS read, no per-iter VALU mask recompute.
// Node mask from stage-time shuffle-reduce. Then tanh update; mode 1 ->
// next-pass hv/hw projections; mode 2 -> fused readout.
__global__ __launch_bounds__(256, 6) void k_pass(const float* __restrict__ edges,
                                                 const float* __restrict__ We,
                                                 const float* __restrict__ Wu,
                                                 const float* __restrict__ Wv,
                                                 const float* __restrict__ Ww,
                                                 const float* __restrict__ Wr,
                                                 const float* __restrict__ nodes,
                                                 float* __restrict__ hv_io,
                                                 const float* __restrict__ hw_in,
                                                 float* __restrict__ hw_out,
                                                 const float* __restrict__ hid_in,
                                                 float* __restrict__ hidden,
                                                 float* __restrict__ out,
                                                 int mode) {
    __shared__ float4 e_s[2][N_];          // 4 KB
    __shared__ float  asum_part[4];        // per-wave partial row sums
    __shared__ unsigned qmask_s[2][4];     // per-row edge-mask bits (4x32)
    __shared__ float  hid_s[2][H_];
    __shared__ float  msg_s[2][H_];
    __shared__ float  hn_s[2][H_];
    __shared__ float  nod_s[2][H_];        // mode 2 only
    __shared__ float  red_s[2][H_];        // mode 2 only

    const int row0 = blockIdx.x * 2;
    const int b = row0 >> 7;
    const int t = threadIdx.x, r = t >> 7, j = t & 127;
    const int wv = t >> 6, lane = t & 63;
    const int row = row0 + r;
    const bool act = (j < H_);

    {   // stage both rows' edges; ballot edge-mask bits; reduce row sums
        const float4* eg = (const float4*)(edges + (size_t)row0 * N_ * 4);
        const float4 e = eg[t];                   // t == r*128 + j, coalesced
        e_s[r][j] = e;                            // wave wv, lane l -> w = (wv&1)*64 + l
        float s = (e.x + e.y) + (e.z + e.w);
        const unsigned long long bal = __ballot(s != 0.f);
        if (lane == 0) {
            qmask_s[wv >> 1][(wv & 1) * 2]     = (unsigned)bal;
            qmask_s[wv >> 1][(wv & 1) * 2 + 1] = (unsigned)(bal >> 32);
        }
#pragma unroll
        for (int off = 32; off > 0; off >>= 1) s += __shfl_down(s, off);
        if (lane == 0) asum_part[wv] = s;
    }
    {   // stage pre-update hidden rows (50 float4); nodes too if readout pass
        const float4* hg = (const float4*)(hid_in + (size_t)row0 * H_);
        if (t < 50) ((float4*)hid_s)[t] = hg[t];
        if (mode == 2) {
            const float4* ng = (const float4*)(nodes + (size_t)row0 * H_);
            if (t < 50) ((float4*)nod_s)[t] = ng[t];
        }
    }
    __syncthreads();

    const float nm = ((asum_part[2 * r] + asum_part[2 * r + 1]) != 0.f) ? 1.f : 0.f;

    if (act) {
        const float hvv = hv_io[(size_t)row * H_ + j];
        const float we0 = We[0 * H_ + j], we1 = We[1 * H_ + j];
        const float we2 = We[2 * H_ + j], we3 = We[3 * H_ + j];
        const float* hwp = hw_in + (size_t)b * N_ * H_ + j;
        float acc = 0.f;
        for (int c = 0; c < 4; ++c) {             // 4 chunks of 32 w
            const unsigned mq =
                __builtin_amdgcn_readfirstlane(qmask_s[r][c]);  // SGPR, uniform
            const float4* ec = &e_s[r][c * 32];
            const float*  hc = hwp + (size_t)(c * 32) * H_;
#pragma unroll 8
            for (int w8 = 0; w8 < 32; ++w8) {
                const float4 e = ec[w8];          // LDS b128 broadcast
                const float  hww = hc[w8 * H_];   // coalesced 400B/wave-pair
                const float  m = ((mq >> w8) & 1u) ? 1.f : 0.f;  // SALU cselect
                float p = hvv + hww;
                p = fmaf(e.x, we0, p);
                p = fmaf(e.y, we1, p);
                p = fmaf(e.z, we2, p);
                p = fmaf(e.w, we3, p);
                acc = fmaf(m, fmaxf(p, 0.f), acc);
            }
        }
        msg_s[r][j] = acc;
    }
    __syncthreads();

    if (act) {
        const float4* h4p = (const float4*)hid_s[r];
        const float4* m4p = (const float4*)msg_s[r];
        float u = 0.f;
#pragma unroll 5
        for (int k4 = 0; k4 < 25; ++k4) {
            const float4 h4 = h4p[k4];
            const int k = k4 * 4;
            u = fmaf(h4.x, Wu[(k + 0) * H_ + j], u);
            u = fmaf(h4.y, Wu[(k + 1) * H_ + j], u);
            u = fmaf(h4.z, Wu[(k + 2) * H_ + j], u);
            u = fmaf(h4.w, Wu[(k + 3) * H_ + j], u);
        }
#pragma unroll 5
        for (int k4 = 0; k4 < 25; ++k4) {
            const float4 m4 = m4p[k4];
            const int k = H_ + k4 * 4;
            u = fmaf(m4.x, Wu[(k + 0) * H_ + j], u);
            u = fmaf(m4.y, Wu[(k + 1) * H_ + j], u);
            u = fmaf(m4.z, Wu[(k + 2) * H_ + j], u);
            u = fmaf(m4.w, Wu[(k + 3) * H_ + j], u);
        }
        const float nh = (nm != 0.f) ? tanhf(u) : hid_s[r][j];
        hn_s[r][j] = nh;
        if (mode == 1) hidden[(size_t)row * H_ + j] = nh;
    }
    __syncthreads();

    if (mode == 1) {        // next pass's hv/hw from fresh hidden (own rows)
        if (act) {
            const float4* h4p = (const float4*)hn_s[r];
            float va = 0.f, wa = 0.f;
#pragma unroll 5
            for (int k4 = 0; k4 < 25; ++k4) {
                const float4 h4 = h4p[k4];
                const int k = k4 * 4;
                va = fmaf(h4.x, Wv[(k + 0) * H_ + j], va);
                wa = fmaf(h4.x, Ww[(k + 0) * H_ + j], wa);
                va = fmaf(h4.y, Wv[(k + 1) * H_ + j], va);
                wa = fmaf(h4.y, Ww[(k + 1) * H_ + j], wa);
                va = fmaf(h4.z, Wv[(k + 2) * H_ + j], va);
                wa = fmaf(h4.z, Ww[(k + 2) * H_ + j], wa);
                va = fmaf(h4.w, Wv[(k + 3) * H_ + j], va);
                wa = fmaf(h4.w, Ww[(k + 3) * H_ + j], wa);
            }
            hv_io[(size_t)row * H_ + j] = va;     // row-local: safe in-place
            hw_out[(size_t)row * H_ + j] = wa;    // double-buffered
        }
    } else {                // mode 2: fused readout
        if (act) {
            const float4* h4p = (const float4*)hn_s[r];
            const float4* n4p = (const float4*)nod_s[r];
            float u = 0.f;
#pragma unroll 5
            for (int k4 = 0; k4 < 25; ++k4) {
                const float4 h4 = h4p[k4];
                const int k = k4 * 4;
                u = fmaf(h4.x, Wr[(k + 0) * H_ + j], u);
                u = fmaf(h4.y, Wr[(k + 1) * H_ + j], u);
                u = fmaf(h4.z, Wr[(k + 2) * H_ + j], u);
                u = fmaf(h4.w, Wr[(k + 3) * H_ + j], u);
            }
#pragma unroll 5
            for (int k4 = 0; k4 < 25; ++k4) {
                const float4 n4 = n4p[k4];
                const int k = H_ + k4 * 4;
                u = fmaf(n4.x, Wr[(k + 0) * H_ + j], u);
                u = fmaf(n4.y, Wr[(k + 1) * H_ + j], u);
                u = fmaf(n4.z, Wr[(k + 2) * H_ + j], u);
                u = fmaf(n4.w, Wr[(k + 3) * H_ + j], u);
            }
            red_s[r][j] = nm * fmaxf(u, 0.f);
        }
        __syncthreads();
        if (t < H_) atomicAdd(out + b * H_ + t, red_s[0][t] + red_s[1][t]);
    }
}

// ---------------------------------------------------------------------------
extern "C" void kernel_launch(void* const* d_in, const int* in_sizes, int n_in,
                              void* d_out, int out_size, void* d_ws, size_t ws_size,
                              hipStream_t stream) {
    const float* nodes = (const float*)d_in[0];
    const float* edges = (const float*)d_in[1];
    const float* Wv    = (const float*)d_in[2];
    const float* Ww    = (const float*)d_in[3];
    const float* We    = (const float*)d_in[4];
    const float* Wu    = (const float*)d_in[5];
    const float* Wr    = (const float*)d_in[6];
    float* out = (float*)d_out;

    float* hidden = (float*)d_ws;     // RH
    float* hv     = hidden + RH;      // RH
    float* hwA    = hv + RH;          // RH
    float* hwB    = hwA + RH;         // RH

    k_proj0<<<ROWS / 2, 256, 0, stream>>>(nodes, Wv, Ww, hv, hwA, out);

    k_pass<<<ROWS / 2, 256, 0, stream>>>(edges, We, Wu, Wv, Ww, Wr, nodes,
                                         hv, hwA, hwB, nodes, hidden, out, 1);
    k_pass<<<ROWS / 2, 256, 0, stream>>>(edges, We, Wu, Wv, Ww, Wr, nodes,
                                         hv, hwB, hwA, hidden, hidden, out, 1);
    k_pass<<<ROWS / 2, 256, 0, stream>>>(edges, We, Wu, Wv, Ww, Wr, nodes,
                                         hv, hwA, hwB, hidden, hidden, out, 2);
}